// Round 8
// baseline (643.742 us; speedup 1.0000x reference)
//
#include <hip/hip_runtime.h>

#define T_LEN 65536
// Certificate windows (proven at 96/48 with absmax 0.0 across R17-R23's
// packed math). Encoder math below is byte-identical to R23's passing version.
#define KA 96
#define KB 48

typedef float v2f __attribute__((ext_vector_type(2)));
typedef float v4f __attribute__((ext_vector_type(4)));

__device__ __forceinline__ float rl(float v, int k) {
    return __uint_as_float(__builtin_amdgcn_readlane(__float_as_uint(v), (unsigned)k));
}
__device__ __forceinline__ float sigf(float x) {
    return __builtin_amdgcn_rcpf(1.0f + __expf(-x));
}
__device__ __forceinline__ float tanh_fast(float x) {
    return fmaf(2.0f, __builtin_amdgcn_rcpf(1.0f + __expf(-2.0f * x)), -1.0f);
}
__device__ __forceinline__ v2f pk_fma(v2f a, v2f b, v2f c) {
    return __builtin_elementwise_fma(a, b, c);   // v_pk_fma_f32
}
#define SV(a, i, j) __builtin_shufflevector((a), (a), (i), (j))

// R24 = R23 frozen + MEASUREMENT dispatches. Three structurally different
// decoders (R16 issue-heavy, R17 LDS-heavy, R23 both-light) all land ~94us
// and the active CU is ~2/3 stalled (VALUBusy_scaled ~33%) -> serial
// latency-chain model. But every model fit has had 2 free parameters:
// t_stop (dec steps to convergence), E (encoder share), d (dec ns/step).
// This round measures them via two extra template instances with the exit
// disabled and DSTEPS forced to 64/320, outputs to d_ws:
//   d = (dur320 - dur64)/256;  E = dur64 - 64d;  t_stop = (dur_main - E)/d.
// Graded dur rises ~200us THIS ROUND ONLY (diag dispatches in the graph).
#define PIN8(A, O) asm volatile("" :                                  \
    "+v"((A)[(O)+0]), "+v"((A)[(O)+1]), "+v"((A)[(O)+2]), "+v"((A)[(O)+3]), \
    "+v"((A)[(O)+4]), "+v"((A)[(O)+5]), "+v"((A)[(O)+6]), "+v"((A)[(O)+7]))

// one encoder step: packed matvec + raw-preact store (R3 barrier structure)
#define ENC_STEP(T_IDX) {                                           \
    v2f A0 = {fmaf(x_cur, wih_e, b_e), 0.f};                        \
    v2f A1 = {0.f, 0.f}, A2 = {0.f, 0.f}, A3 = {0.f, 0.f};          \
    _Pragma("unroll")                                               \
    for (int j = 0; j < 16; ++j) {                                  \
        v4f hp = hbE[j];                                            \
        v2f hl = SV(hp, 0, 1), hh = SV(hp, 2, 3);                   \
        v2f wl = SV(ew[j], 0, 1), wh = SV(ew[j], 2, 3);             \
        if (j & 1) { A2 = pk_fma(wl, hl, A2); A3 = pk_fma(wh, hh, A3); } \
        else       { A0 = pk_fma(wl, hl, A0); A1 = pk_fma(wh, hh, A1); } \
    }                                                               \
    v2f As = (A0 + A1) + (A2 + A3);                                 \
    g_enc[rep][(T_IDX) & 1][rtid] = As.x + As.y; }

#define ENC_UPD(T_IDX) {                                            \
    const float* gb = g_enc[rep][(T_IDX) & 1];                      \
    float ig = sigf(gb[lane]);                                      \
    float fg = sigf(gb[64  + lane]);                                \
    float cg = tanh_fast(gb[128 + lane]);                           \
    float og = sigf(gb[192 + lane]);                                \
    c_e = fmaf(fg, c_e, ig * cg);                                   \
    h_e = og * tanh_fast(c_e);                                      \
    hEw[lane] = h_e; }

// DSTEPS == 0: normal graded kernel (early exit, writes out, tail fill).
// DSTEPS  > 0: diagnostic — exactly DSTEPS decoder steps, exit disabled
//              (check kept live via asm), no tail fill, out == d_ws.
template<int DSTEPS>
__global__ __attribute__((amdgpu_waves_per_eu(1, 2)))
__launch_bounds__(512) void lstm_ae_kernel(
    const float* __restrict__ x,
    const float* __restrict__ enc_wih, const float* __restrict__ enc_whh,
    const float* __restrict__ enc_b,
    const float* __restrict__ dec_wih, const float* __restrict__ dec_whh,
    const float* __restrict__ dec_b,
    const float* __restrict__ out_w, const float* __restrict__ out_b,
    float* __restrict__ out)
{
    const int tid  = threadIdx.x;      // 0..511
    const int lane = tid & 63;
    const int wave = tid >> 6;         // 0..7
    const int rep  = wave >> 2;        // 0 = replica A, 1 = replica B
    const int rtid = ((wave & 3) << 6) | lane;   // row within replica (0..255)

    __shared__ __align__(16) float g_enc[2][2][256];  // [rep][buf][row]
    __shared__ __align__(16) float g_dec[2][512];
    __shared__ __align__(16) float henc[8][64];       // per-wave enc h copy
    // dec h: per-wave, segment-padded (seg s at dword s*36; +4 pad de-aliases
    // the 4 broadcast addresses of a b128 read onto distinct bank groups).
    __shared__ __align__(16) float hdec[8][144];
    __shared__ float zA[64], zB[64];
    __shared__ int s_fail;

    if (tid == 0) s_fail = 0;

    // ---------------- encoder weights (per-replica row rtid) ----------------
    v4f ew[16];
    {
        const float* erow = enc_whh + rtid * 64;
        #pragma unroll
        for (int j = 0; j < 16; ++j) ew[j] = ((const v4f*)erow)[j];
    }
    const float wih_e = enc_wih[rtid];
    const float b_e   = enc_b[rtid];

    float* hEw = &henc[wave][0];
    const v4f* hbE = (const v4f*)hEw;
    hEw[lane] = 0.f;

    // ---------------- truncated two-replica encoder (R17 math) --------------
    const int myStart = rep ? (T_LEN - KB) : (T_LEN - KA);
    float h_e = 0.f, c_e = 0.f;
    float x_cur = x[T_LEN - KA];

    for (int t = T_LEN - KA; t < T_LEN; ++t) {
        PIN8(ew, 0); PIN8(ew, 8);
        if (t >= myStart) ENC_STEP(t)                  // wave-uniform predicate
        float x_nxt = x[(t + 1 < T_LEN) ? t + 1 : T_LEN - 1];
        __syncthreads();
        if (t >= myStart) ENC_UPD(t)
        x_cur = x_nxt;
    }
    if (wave == 0) zA[lane] = h_e;
    if (wave == 4) zB[lane] = h_e;
    __syncthreads();
    if (fabsf(zA[lane] - zB[lane]) > 1e-6f) s_fail = 1;   // benign race
    __syncthreads();

    if (s_fail) {   // certificate failed: full-length deterministic fallback
        h_e = 0.f; c_e = 0.f;
        hEw[lane] = 0.f;
        x_cur = x[0];
        for (int t = 0; t < T_LEN; ++t) {
            PIN8(ew, 0); PIN8(ew, 8);
            ENC_STEP(t)
            float x_nxt = x[(t + 1 < T_LEN) ? t + 1 : T_LEN - 1];
            __syncthreads();
            ENC_UPD(t)
            x_cur = x_nxt;
        }
        if (wave == 0) zA[lane] = h_e;
        __syncthreads();
    }
    h_e = zA[lane];                     // z[lane] in every wave

    // ============ decoder: structure Z (4-lane column-split, R23) ============
    const int s2    = lane & 3;
    const int rg    = lane >> 2;
    const int myrow = (wave << 6) + (s2 << 4) + rg;

    v4f wd[32];   // [pass p][j]: dec_whh[row(p)][32*s2 + 4j ..]
    #pragma unroll
    for (int p2 = 0; p2 < 4; ++p2) {
        const int r = (wave << 6) + (p2 << 4) + rg;
        const v4f* wr = (const v4f*)(dec_whh + r * 128 + (s2 << 5));
        #pragma unroll
        for (int j = 0; j < 8; ++j) wd[p2 * 8 + j] = wr[j];
    }

    // constant input projection for MY row
    float xgd = dec_b[myrow];
    {
        const float* wr = dec_wih + myrow * 64;
        #pragma unroll
        for (int k = 0; k < 64; ++k)
            xgd = fmaf(rl(h_e, k), wr[k], xgd);
    }
    const float ow0 = out_w[lane];
    const float ow1 = out_w[lane + 64];
    const float ob  = out_b[0];

    float* hDw = &hdec[wave][0];
    for (int k2 = lane; k2 < 144; k2 += 64) hDw[k2] = 0.f;  // wave-private init
    const v4f* hb4 = (const v4f*)(hDw + s2 * 36);
    const int hw0 = ((lane >> 5) * 36) + (lane & 31);        // unit 'lane'
    const int hw1 = ((2 + (lane >> 5)) * 36) + (lane & 31);  // unit 'lane+64'

    float h0 = 0.f, h1 = 0.f, c0 = 0.f, c1 = 0.f;
    float h0p = 0.f, h1p = 0.f;
    int t_stop = T_LEN;

    const int tLim = (DSTEPS == 0) ? T_LEN : DSTEPS;
    for (int t = 0; t < tLim; ++t) {
        PIN8(wd, 0); PIN8(wd, 8); PIN8(wd, 16); PIN8(wd, 24);
        // load my h-segment once (8 broadcast-4 b128), reuse over 4 passes
        v4f hs0 = hb4[0], hs1 = hb4[1], hs2 = hb4[2], hs3 = hb4[3];
        v4f hs4 = hb4[4], hs5 = hb4[5], hs6 = hb4[6], hs7 = hb4[7];
        float myres = xgd;
        #pragma unroll
        for (int p2 = 0; p2 < 4; ++p2) {
            v2f a = {0.f, 0.f}, b2 = {0.f, 0.f};
            #pragma unroll
            for (int j = 0; j < 8; ++j) {
                v4f w4 = wd[p2 * 8 + j];
                v4f h4 = (j==0)?hs0:(j==1)?hs1:(j==2)?hs2:(j==3)?hs3:
                         (j==4)?hs4:(j==5)?hs5:(j==6)?hs6:hs7;
                a  = pk_fma(SV(w4, 0, 1), SV(h4, 0, 1), a);
                b2 = pk_fma(SV(w4, 2, 3), SV(h4, 2, 3), b2);
            }
            v2f sres = a + b2;
            float r = sres.x + sres.y;
            r += __shfl_xor(r, 1);
            r += __shfl_xor(r, 2);
            if (s2 == p2) myres += r;          // keep my pass (cndmask)
        }
        g_dec[t & 1][myrow] = myres;           // one row per lane
        __syncthreads();                       // the ONLY barrier per step

        // ---- redundant gate update in all 8 waves: units lane, lane+64 ----
        const float* gb = g_dec[t & 1];
        float i0 = sigf(gb[lane]);
        float f0 = sigf(gb[128 + lane]);
        float m0 = tanh_fast(gb[256 + lane]);
        float o0 = sigf(gb[384 + lane]);
        float i1 = sigf(gb[64  + lane]);
        float f1 = sigf(gb[192 + lane]);
        float m1 = tanh_fast(gb[320 + lane]);
        float o1 = sigf(gb[448 + lane]);
        c0 = fmaf(f0, c0, i0 * m0);  h0 = o0 * tanh_fast(c0);
        c1 = fmaf(f1, c1, i1 * m1);  h1 = o1 * tanh_fast(c1);
        hDw[hw0] = h0;                          // refresh segment-padded copy
        hDw[hw1] = h1;

        // out[t] duty rotates over the 8 waves (diag: out == d_ws)
        if (((t ^ wave) & 7) == 0) {
            float p = fmaf(h0, ow0, h1 * ow1);
            #pragma unroll
            for (int off = 32; off > 0; off >>= 1)
                p += __shfl_xor(p, off);
            if (lane == 0) out[t] = p + ob;
        }

        // fixed-point exit, cadence 2, threshold 1e-5 (drift bound ~8e-5 <<
        // 9.8e-4; mechanism HW-validated R12-R23). In diag mode the check is
        // computed (kept live via asm, rule #17: skip-ablation DCEs upstream)
        // but never taken, so per-step cost matches the graded kernel.
        if ((t & 1) == 1) {
            float d = fmaxf(fabsf(h0 - h0p), fabsf(h1 - h1p));
            h0p = h0; h1p = h1;
            if (DSTEPS == 0) {
                if (__ballot(d > 1e-5f) == 0ull) { t_stop = t; break; }
            } else {
                asm volatile("" :: "v"(d));
            }
        }
    }

    // fill the converged tail with the fixed-point output (graded mode only)
    if (DSTEPS == 0 && t_stop < T_LEN) {
        float p = fmaf(h0, ow0, h1 * ow1);
        #pragma unroll
        for (int off = 32; off > 0; off >>= 1)
            p += __shfl_xor(p, off);
        float ov = p + ob;
        for (int t = t_stop + 1 + tid; t < T_LEN; t += 512)
            out[t] = ov;
    }
}

extern "C" void kernel_launch(void* const* d_in, const int* in_sizes, int n_in,
                              void* d_out, int out_size, void* d_ws, size_t ws_size,
                              hipStream_t stream) {
    const float* x       = (const float*)d_in[0];
    const float* enc_wih = (const float*)d_in[1];
    const float* enc_whh = (const float*)d_in[2];
    const float* enc_b   = (const float*)d_in[3];
    const float* dec_wih = (const float*)d_in[4];
    const float* dec_whh = (const float*)d_in[5];
    const float* dec_b   = (const float*)d_in[6];
    const float* out_w   = (const float*)d_in[7];
    const float* out_b   = (const float*)d_in[8];

    // graded kernel (unchanged R23 math)
    hipLaunchKernelGGL((lstm_ae_kernel<0>), dim3(1), dim3(512), 0, stream,
                       x, enc_wih, enc_whh, enc_b,
                       dec_wih, dec_whh, dec_b,
                       out_w, out_b, (float*)d_out);

    // measurement dispatches: fixed 64 / 320 decoder steps, outputs to d_ws.
    // d = (dur320 - dur64)/256; E = dur64 - 64d; t_stop = (dur_main - E)/d.
    if (d_ws != nullptr && ws_size >= 2048) {
        hipLaunchKernelGGL((lstm_ae_kernel<64>), dim3(1), dim3(512), 0, stream,
                           x, enc_wih, enc_whh, enc_b,
                           dec_wih, dec_whh, dec_b,
                           out_w, out_b, (float*)d_ws);
        hipLaunchKernelGGL((lstm_ae_kernel<320>), dim3(1), dim3(512), 0, stream,
                           x, enc_wih, enc_whh, enc_b,
                           dec_wih, dec_whh, dec_b,
                           out_w, out_b, (float*)d_ws);
    }
}

// Round 9
// 209.000 us; speedup vs baseline: 3.0801x; 3.0801x over previous
//
#include <hip/hip_runtime.h>

#define T_LEN 65536
// Certificate windows (proven at 96/48, absmax 0.0, R17-R23). Encoder rounding
// changes this round (4-rows-per-lane packed matvec) but replicas A/B share
// the new rounding, so the 1e-6 agreement certificate remains valid.
#define KA 96
#define KB 48

typedef float v2f __attribute__((ext_vector_type(2)));
typedef float v4f __attribute__((ext_vector_type(4)));

__device__ __forceinline__ float rl(float v, int k) {
    return __uint_as_float(__builtin_amdgcn_readlane(__float_as_uint(v), (unsigned)k));
}
__device__ __forceinline__ float sigf(float x) {
    return __builtin_amdgcn_rcpf(1.0f + __expf(-x));
}
__device__ __forceinline__ float tanh_fast(float x) {
    return fmaf(2.0f, __builtin_amdgcn_rcpf(1.0f + __expf(-2.0f * x)), -1.0f);
}
__device__ __forceinline__ v2f pk_fma(v2f a, v2f b, v2f c) {
    return __builtin_elementwise_fma(a, b, c);   // v_pk_fma_f32
}
#define SV(a, i, j) __builtin_shufflevector((a), (a), (i), (j))

#define PIN8(A, O) asm volatile("" :                                  \
    "+v"((A)[(O)+0]), "+v"((A)[(O)+1]), "+v"((A)[(O)+2]), "+v"((A)[(O)+3]), \
    "+v"((A)[(O)+4]), "+v"((A)[(O)+5]), "+v"((A)[(O)+6]), "+v"((A)[(O)+7]))

// ===================== R25 kernel 1: barrier-free encoder ====================
// R24 measurement: decoder converges in ~22-70 steps; ~60-75us of R23's 94us
// was ENCODER + prologue (96 barrier-synced steps). H=64 = one wave: lane l
// owns unit l, computes gate rows l,64+l,128+l,192+l entirely in registers --
// gates never touch LDS, NO __syncthreads in the step loop (h-broadcast is a
// wave-internal ds_write -> ds_read, same-wave DS ops are in-order). Replicas
// A/B run concurrently on waves 0/1. Own kernel so waves_per_eu(1,1) gives
// the 512-reg budget for 256 weight VGPRs without constraining the decoder.

// one barrier-free encoder step: 4 gate rows in-register, h via own-wave LDS
#define ENC1_STEP(XV) {                                                 \
    float xv = (XV);                                                    \
    v2f ai0 = {fmaf(xv, xi, bi),  0.f}, ai1 = {0.f, 0.f};               \
    v2f af0 = {fmaf(xv, xf, bf2), 0.f}, af1 = {0.f, 0.f};               \
    v2f ag0 = {fmaf(xv, xg, bg),  0.f}, ag1 = {0.f, 0.f};               \
    v2f ao0 = {fmaf(xv, xo, bo),  0.f}, ao1 = {0.f, 0.f};               \
    _Pragma("unroll")                                                   \
    for (int j = 0; j < 16; ++j) {                                      \
        v4f hq = hb[j];                          /* broadcast b128 */   \
        v2f hl = SV(hq, 0, 1), hh = SV(hq, 2, 3);                       \
        ai0 = pk_fma(SV(wi[j], 0, 1), hl, ai0);                         \
        ai1 = pk_fma(SV(wi[j], 2, 3), hh, ai1);                         \
        af0 = pk_fma(SV(wf[j], 0, 1), hl, af0);                         \
        af1 = pk_fma(SV(wf[j], 2, 3), hh, af1);                         \
        ag0 = pk_fma(SV(wg[j], 0, 1), hl, ag0);                         \
        ag1 = pk_fma(SV(wg[j], 2, 3), hh, ag1);                         \
        ao0 = pk_fma(SV(wo[j], 0, 1), hl, ao0);                         \
        ao1 = pk_fma(SV(wo[j], 2, 3), hh, ao1);                         \
    }                                                                   \
    v2f si = ai0 + ai1, sf = af0 + af1, sg = ag0 + ag1, so = ao0 + ao1; \
    float ig = sigf(si.x + si.y);                                       \
    float fg = sigf(sf.x + sf.y);                                       \
    float gg = tanh_fast(sg.x + sg.y);                                  \
    float og = sigf(so.x + so.y);                                       \
    c = fmaf(fg, c, ig * gg);                                           \
    h = og * tanh_fast(c);                                              \
    hw[lane] = h; }                      /* in-order same-wave DS */

#define ENC1_PINS  PIN8(wi,0); PIN8(wi,8); PIN8(wf,0); PIN8(wf,8); \
                   PIN8(wg,0); PIN8(wg,8); PIN8(wo,0); PIN8(wo,8);

__global__ __attribute__((amdgpu_waves_per_eu(1, 1)))
__launch_bounds__(128) void enc_kernel(
    const float* __restrict__ x,
    const float* __restrict__ enc_wih, const float* __restrict__ enc_whh,
    const float* __restrict__ enc_b,
    float* __restrict__ z_out)
{
    const int tid  = threadIdx.x;     // 0..127
    const int lane = tid & 63;
    const int wave = tid >> 6;        // 0 = replica A, 1 = replica B

    __shared__ __align__(16) float hA[64], hB[64];
    __shared__ float s_x[KA];
    __shared__ float zsh[2][64];
    __shared__ int s_fail;
    if (tid == 0) s_fail = 0;

    // 4 gate rows of unit 'lane', fully register-resident (256 VGPR)
    v4f wi[16], wf[16], wg[16], wo[16];
    {
        const v4f* ri = (const v4f*)(enc_whh + lane * 64);
        const v4f* rf = (const v4f*)(enc_whh + (64  + lane) * 64);
        const v4f* rg = (const v4f*)(enc_whh + (128 + lane) * 64);
        const v4f* ro = (const v4f*)(enc_whh + (192 + lane) * 64);
        #pragma unroll
        for (int j = 0; j < 16; ++j) {
            wi[j] = ri[j]; wf[j] = rf[j]; wg[j] = rg[j]; wo[j] = ro[j];
        }
    }
    const float bi  = enc_b[lane],        bf2 = enc_b[64 + lane];
    const float bg  = enc_b[128 + lane],  bo  = enc_b[192 + lane];
    const float xi  = enc_wih[lane],      xf  = enc_wih[64 + lane];
    const float xg  = enc_wih[128 + lane],xo  = enc_wih[192 + lane];

    if (tid < KA) s_x[tid] = x[T_LEN - KA + tid];
    float* hw = wave ? hB : hA;
    const v4f* hb = (const v4f*)hw;
    hw[lane] = 0.f;
    __syncthreads();                      // s_x staged (h copy is wave-internal)

    float h = 0.f, c = 0.f;
    const int K  = wave ? KB : KA;
    const int x0 = KA - K;
    for (int k = 0; k < K; ++k) {         // NO barrier in this loop
        ENC1_PINS
        ENC1_STEP(s_x[x0 + k])
    }
    zsh[wave][lane] = h;
    __syncthreads();
    if (fabsf(zsh[0][lane] - zsh[1][lane]) > 1e-6f) s_fail = 1;  // benign race
    __syncthreads();

    if (s_fail) {
        // deterministic full-length fallback, both waves redundantly
        h = 0.f; c = 0.f; hw[lane] = 0.f;
        for (int base = 0; base < T_LEN; base += KA) {
            const int cnt = (base + KA <= T_LEN) ? KA : (T_LEN - base);
            __syncthreads();
            if (tid < cnt) s_x[tid] = x[base + tid];
            __syncthreads();
            for (int k = 0; k < cnt; ++k) {
                ENC1_PINS
                ENC1_STEP(s_x[k])
            }
        }
        zsh[0][lane] = h;                 // both waves: identical bits, benign
        __syncthreads();
    }
    if (tid < 64) z_out[tid] = zsh[0][tid];
}

// ===================== R25 kernel 2: R23 decoder (unchanged) =================
__global__ __attribute__((amdgpu_waves_per_eu(1, 2)))
__launch_bounds__(512) void dec_kernel(
    const float* __restrict__ z_buf,
    const float* __restrict__ dec_wih, const float* __restrict__ dec_whh,
    const float* __restrict__ dec_b,
    const float* __restrict__ out_w, const float* __restrict__ out_b,
    float* __restrict__ out)
{
    const int tid  = threadIdx.x;      // 0..511
    const int lane = tid & 63;
    const int wave = tid >> 6;         // 0..7

    __shared__ __align__(16) float g_dec[2][512];
    // dec h: per-wave, segment-padded (seg s at dword s*36; +4 pad de-aliases
    // the 4 broadcast addresses of a b128 read onto distinct bank groups).
    __shared__ __align__(16) float hdec[8][144];

    // structure Z (4-lane column-split, R23-proven)
    const int s2    = lane & 3;
    const int rg    = lane >> 2;
    const int myrow = (wave << 6) + (s2 << 4) + rg;

    v4f wd[32];   // [pass p][j]: dec_whh[row(p)][32*s2 + 4j ..]
    #pragma unroll
    for (int p2 = 0; p2 < 4; ++p2) {
        const int r = (wave << 6) + (p2 << 4) + rg;
        const v4f* wr = (const v4f*)(dec_whh + r * 128 + (s2 << 5));
        #pragma unroll
        for (int j = 0; j < 8; ++j) wd[p2 * 8 + j] = wr[j];
    }

    const float h_e = z_buf[lane];     // embedding z from enc_kernel via d_ws

    // constant input projection for MY row
    float xgd = dec_b[myrow];
    {
        const float* wr = dec_wih + myrow * 64;
        #pragma unroll
        for (int k = 0; k < 64; ++k)
            xgd = fmaf(rl(h_e, k), wr[k], xgd);
    }
    const float ow0 = out_w[lane];
    const float ow1 = out_w[lane + 64];
    const float ob  = out_b[0];

    float* hDw = &hdec[wave][0];
    for (int k2 = lane; k2 < 144; k2 += 64) hDw[k2] = 0.f;  // wave-private init
    const v4f* hb4 = (const v4f*)(hDw + s2 * 36);
    const int hw0 = ((lane >> 5) * 36) + (lane & 31);        // unit 'lane'
    const int hw1 = ((2 + (lane >> 5)) * 36) + (lane & 31);  // unit 'lane+64'

    float h0 = 0.f, h1 = 0.f, c0 = 0.f, c1 = 0.f;
    float h0p = 0.f, h1p = 0.f;
    int t_stop = T_LEN;

    for (int t = 0; t < T_LEN; ++t) {
        PIN8(wd, 0); PIN8(wd, 8); PIN8(wd, 16); PIN8(wd, 24);
        v4f hs0 = hb4[0], hs1 = hb4[1], hs2 = hb4[2], hs3 = hb4[3];
        v4f hs4 = hb4[4], hs5 = hb4[5], hs6 = hb4[6], hs7 = hb4[7];
        float myres = xgd;
        #pragma unroll
        for (int p2 = 0; p2 < 4; ++p2) {
            v2f a = {0.f, 0.f}, b2 = {0.f, 0.f};
            #pragma unroll
            for (int j = 0; j < 8; ++j) {
                v4f w4 = wd[p2 * 8 + j];
                v4f h4 = (j==0)?hs0:(j==1)?hs1:(j==2)?hs2:(j==3)?hs3:
                         (j==4)?hs4:(j==5)?hs5:(j==6)?hs6:hs7;
                a  = pk_fma(SV(w4, 0, 1), SV(h4, 0, 1), a);
                b2 = pk_fma(SV(w4, 2, 3), SV(h4, 2, 3), b2);
            }
            v2f sres = a + b2;
            float r = sres.x + sres.y;
            r += __shfl_xor(r, 1);
            r += __shfl_xor(r, 2);
            if (s2 == p2) myres += r;          // keep my pass (cndmask)
        }
        g_dec[t & 1][myrow] = myres;           // one row per lane
        __syncthreads();                       // the ONLY barrier per step

        const float* gb = g_dec[t & 1];
        float i0 = sigf(gb[lane]);
        float f0 = sigf(gb[128 + lane]);
        float m0 = tanh_fast(gb[256 + lane]);
        float o0 = sigf(gb[384 + lane]);
        float i1 = sigf(gb[64  + lane]);
        float f1 = sigf(gb[192 + lane]);
        float m1 = tanh_fast(gb[320 + lane]);
        float o1 = sigf(gb[448 + lane]);
        c0 = fmaf(f0, c0, i0 * m0);  h0 = o0 * tanh_fast(c0);
        c1 = fmaf(f1, c1, i1 * m1);  h1 = o1 * tanh_fast(c1);
        hDw[hw0] = h0;
        hDw[hw1] = h1;

        if (((t ^ wave) & 7) == 0) {
            float p = fmaf(h0, ow0, h1 * ow1);
            #pragma unroll
            for (int off = 32; off > 0; off >>= 1)
                p += __shfl_xor(p, off);
            if (lane == 0) out[t] = p + ob;
        }

        // fixed-point exit, cadence 2, threshold 1e-5 (drift bound ~8e-5 <<
        // 9.8e-4; mechanism HW-validated R12-R24; R24 measured convergence at
        // only ~22-70 steps).
        if ((t & 1) == 1) {
            float d = fmaxf(fabsf(h0 - h0p), fabsf(h1 - h1p));
            h0p = h0; h1p = h1;
            if (__ballot(d > 1e-5f) == 0ull) { t_stop = t; break; }
        }
    }

    if (t_stop < T_LEN) {
        float p = fmaf(h0, ow0, h1 * ow1);
        #pragma unroll
        for (int off = 32; off > 0; off >>= 1)
            p += __shfl_xor(p, off);
        float ov = p + ob;
        for (int t = t_stop + 1 + tid; t < T_LEN; t += 512)
            out[t] = ov;
    }
}

extern "C" void kernel_launch(void* const* d_in, const int* in_sizes, int n_in,
                              void* d_out, int out_size, void* d_ws, size_t ws_size,
                              hipStream_t stream) {
    const float* x       = (const float*)d_in[0];
    const float* enc_wih = (const float*)d_in[1];
    const float* enc_whh = (const float*)d_in[2];
    const float* enc_b   = (const float*)d_in[3];
    const float* dec_wih = (const float*)d_in[4];
    const float* dec_whh = (const float*)d_in[5];
    const float* dec_b   = (const float*)d_in[6];
    const float* out_w   = (const float*)d_in[7];
    const float* out_b   = (const float*)d_in[8];

    float* zbuf = (float*)d_ws;   // 64 floats; ws_size >= 2048 proven in R24

    hipLaunchKernelGGL(enc_kernel, dim3(1), dim3(128), 0, stream,
                       x, enc_wih, enc_whh, enc_b, zbuf);
    hipLaunchKernelGGL(dec_kernel, dim3(1), dim3(512), 0, stream,
                       zbuf, dec_wih, dec_whh, dec_b, out_w, out_b,
                       (float*)d_out);
}